// Round 1
// baseline (72.774 us; speedup 1.0000x reference)
//
#include <hip/hip_runtime.h>
#include <math.h>

#define B 64
#define N 16384
#define K 16
#define ROW_WS 48   // floats per row in workspace: c[16], idx[16], m0, pad

// ---------------- Phase 1: per-row top-16 + softmax constants ----------------
// One block per row. Each thread holds 16 strided elements in registers.
// 16 sequential (argmax -> mask) reductions, then one exp-sum reduction.
__global__ __launch_bounds__(1024)
void gtk_phase1(const float* __restrict__ logits, const float* __restrict__ gumbel,
                float* __restrict__ ws) {
  const int b = blockIdx.x;
  const int t = threadIdx.x;
  const int wave = t >> 6;
  const int lane = t & 63;
  const float* lg = logits + (size_t)b * N;
  const float* gm = gumbel + (size_t)b * N;

  float x[16];
#pragma unroll
  for (int s = 0; s < 16; ++s) {
    const int n = t + s * 1024;
    x[s] = lg[n] + gm[n];
  }

  __shared__ float swv[16];
  __shared__ int   swi[16];
  __shared__ float s_topv[K];
  __shared__ int   s_topi[K];

  for (int k = 0; k < K; ++k) {
    // thread-local argmax (ties -> smaller index, scan order is ascending idx)
    float vmax = -INFINITY;
    int   imax = 0x7fffffff;
#pragma unroll
    for (int s = 0; s < 16; ++s) {
      const int n = t + s * 1024;
      if (x[s] > vmax) { vmax = x[s]; imax = n; }
    }
    // wave64 butterfly-free down-reduce (ties -> smaller index)
#pragma unroll
    for (int off = 32; off > 0; off >>= 1) {
      const float ov = __shfl_down(vmax, off);
      const int   oi = __shfl_down(imax, off);
      if (ov > vmax || (ov == vmax && oi < imax)) { vmax = ov; imax = oi; }
    }
    if (lane == 0) { swv[wave] = vmax; swi[wave] = imax; }
    __syncthreads();
    if (t == 0) {
      float bv = swv[0]; int bi = swi[0];
#pragma unroll
      for (int w = 1; w < 16; ++w) {
        if (swv[w] > bv || (swv[w] == bv && swi[w] < bi)) { bv = swv[w]; bi = swi[w]; }
      }
      s_topv[k] = bv; s_topi[k] = bi;
    }
    __syncthreads();
    const int sel = s_topi[k];
    if ((sel & 1023) == t) {
#pragma unroll
      for (int s = 0; s < 16; ++s)
        if (t + s * 1024 == sel) x[s] = -INFINITY;
    }
  }

  // A' = sum over non-top16 of exp((x - m0)/tau); masked slots give exp(-inf)=0
  const float m0 = s_topv[0];
  float part = 0.f;
#pragma unroll
  for (int s = 0; s < 16; ++s) part += __expf((x[s] - m0) * 1.5f);
#pragma unroll
  for (int off = 32; off > 0; off >>= 1) part += __shfl_down(part, off);
  if (lane == 0) swv[wave] = part;
  __syncthreads();

  if (t == 0) {
    float A = 0.f;
#pragma unroll
    for (int w = 0; w < 16; ++w) A += swv[w];
    float e[K];
#pragma unroll
    for (int j = 0; j < K; ++j) e[j] = __expf((s_topv[j] - m0) * 1.5f);
    float c[K];
    float T = 0.f;
#pragma unroll
    for (int j = K - 1; j >= 0; --j) { T += e[j]; c[j] = 1.0f / (A + T); }
    float* wrow = ws + (size_t)b * ROW_WS;
#pragma unroll
    for (int j = 0; j < K; ++j) wrow[j] = c[j];
    int* wi = (int*)(wrow + K);
#pragma unroll
    for (int j = 0; j < K; ++j) wi[j] = s_topi[j];
    wrow[32] = m0;
  }
}

// ---------------- Phase 2: write st (one-hot) and softs (E * c_k) ----------------
// Each thread handles 4 consecutive n; 16 k-planes; float4 loads/stores.
__global__ __launch_bounds__(256)
void gtk_phase2(const float* __restrict__ logits, const float* __restrict__ gumbel,
                const float* __restrict__ ws, float* __restrict__ st,
                float* __restrict__ softs) {
  const int gid = blockIdx.x * 256 + threadIdx.x;
  const int i4  = gid << 2;            // element index into [B*N]
  const int b   = i4 >> 14;            // / N (uniform per block: 16 blocks/row)
  const int n0  = i4 & (N - 1);

  __shared__ float sc[K];
  __shared__ int   si[K];
  __shared__ float sm0;
  if (threadIdx.x < K) {
    sc[threadIdx.x] = ws[(size_t)b * ROW_WS + threadIdx.x];
    si[threadIdx.x] = ((const int*)(ws + (size_t)b * ROW_WS + K))[threadIdx.x];
  }
  if (threadIdx.x == 0) sm0 = ws[(size_t)b * ROW_WS + 32];
  __syncthreads();

  const float4 lv = *(const float4*)(logits + i4);
  const float4 gv = *(const float4*)(gumbel + i4);
  const float m0 = sm0;
  float E[4];
  E[0] = __expf((lv.x + gv.x - m0) * 1.5f);
  E[1] = __expf((lv.y + gv.y - m0) * 1.5f);
  E[2] = __expf((lv.z + gv.z - m0) * 1.5f);
  E[3] = __expf((lv.w + gv.w - m0) * 1.5f);

  // selection step (if any) for each of my 4 elements; K = never selected
  int js[4] = {K, K, K, K};
#pragma unroll
  for (int j = 0; j < K; ++j) {
    const int idx = si[j];
#pragma unroll
    for (int e = 0; e < 4; ++e)
      if (idx == n0 + e) js[e] = j;
  }

  const size_t plane = (size_t)B * N;
#pragma unroll
  for (int k = 0; k < K; ++k) {
    const float ck = sc[k];
    float4 s, h;
    s.x = (js[0] < k) ? 0.f : E[0] * ck;
    s.y = (js[1] < k) ? 0.f : E[1] * ck;
    s.z = (js[2] < k) ? 0.f : E[2] * ck;
    s.w = (js[3] < k) ? 0.f : E[3] * ck;
    h.x = (js[0] == k) ? 1.f : 0.f;
    h.y = (js[1] == k) ? 1.f : 0.f;
    h.z = (js[2] == k) ? 1.f : 0.f;
    h.w = (js[3] == k) ? 1.f : 0.f;
    *(float4*)(softs + k * plane + i4) = s;
    *(float4*)(st    + k * plane + i4) = h;
  }
}

extern "C" void kernel_launch(void* const* d_in, const int* in_sizes, int n_in,
                              void* d_out, int out_size, void* d_ws, size_t ws_size,
                              hipStream_t stream) {
  const float* logits = (const float*)d_in[0];
  const float* gumbel = (const float*)d_in[1];
  float* st    = (float*)d_out;                      // [K,B,N]
  float* softs = st + (size_t)K * B * N;             // [K,B,N]
  float* ws    = (float*)d_ws;

  gtk_phase1<<<B, 1024, 0, stream>>>(logits, gumbel, ws);
  gtk_phase2<<<(B * N / 4) / 256, 256, 0, stream>>>(logits, gumbel, ws, st, softs);
}

// Round 2
// 64.856 us; speedup vs baseline: 1.1221x; 1.1221x over previous
//
#include <hip/hip_runtime.h>
#include <math.h>

#define B 64
#define N 16384
#define K 16
#define ROW_WS 48   // floats per row in workspace: c[16], idx[16] (as int), ..., m0 at [32]

typedef float f4 __attribute__((ext_vector_type(4)));

// ---------------- Phase 1: per-row top-16 + softmax constants ----------------
// One block per row, 1024 threads = 16 waves. Each wave does a barrier-free
// sequential top-16 over its 1024 elements (registers + shuffles), then wave 0
// merges the 256 candidates. Only 2 __syncthreads total.
__global__ __launch_bounds__(1024)
void gtk_phase1(const float* __restrict__ logits, const float* __restrict__ gumbel,
                float* __restrict__ ws) {
  const int b = blockIdx.x;
  const int t = threadIdx.x;
  const int wave = t >> 6;
  const int lane = t & 63;
  const float* lg = logits + (size_t)b * N;
  const float* gm = gumbel + (size_t)b * N;

  float x[16];
#pragma unroll
  for (int s = 0; s < 16; ++s) {
    const int n = t + s * 1024;
    x[s] = lg[n] + gm[n];
  }

  __shared__ float sv[256];   // 16 waves x 16 candidates (values)
  __shared__ int   si[256];   // candidate indices
  __shared__ float ssum[16];  // per-wave exp partial sums (excl. own top-16)

  // --- wave-local sequential top-16, no barriers ---
#pragma unroll 1
  for (int k = 0; k < K; ++k) {
    float vmax = -INFINITY; int imax = 0x7fffffff;
#pragma unroll
    for (int s = 0; s < 16; ++s) {
      if (x[s] > vmax) { vmax = x[s]; imax = t + s * 1024; }  // ascending idx: first wins ties
    }
#pragma unroll
    for (int off = 32; off; off >>= 1) {
      const float ov = __shfl_down(vmax, off);
      const int   oi = __shfl_down(imax, off);
      if (ov > vmax || (ov == vmax && oi < imax)) { vmax = ov; imax = oi; }
    }
    vmax = __shfl(vmax, 0);
    imax = __shfl(imax, 0);
    if (lane == 0) { sv[wave * K + k] = vmax; si[wave * K + k] = imax; }
    if (t == (imax & 1023)) {
      const int ss = imax >> 10;
#pragma unroll
      for (int s = 0; s < 16; ++s) if (s == ss) x[s] = -INFINITY;  // static reg index
    }
  }
  __syncthreads();

  // global m0 = max of wave-leaders (every thread computes; broadcast via LDS reads)
  float m0 = sv[0];
#pragma unroll
  for (int w = 1; w < 16; ++w) m0 = fmaxf(m0, sv[w * K]);

  // per-wave exp partial sums over the non-candidate elements (masked -> exp(-inf)=0)
  float part = 0.f;
#pragma unroll
  for (int s = 0; s < 16; ++s) part += __expf((x[s] - m0) * 1.5f);
#pragma unroll
  for (int off = 32; off; off >>= 1) part += __shfl_down(part, off);
  if (lane == 0) ssum[wave] = part;
  __syncthreads();

  // --- wave 0 merges 256 candidates -> global top-16 sequence + constants ---
  if (wave == 0) {
    float cv[4]; int ci[4];
#pragma unroll
    for (int r = 0; r < 4; ++r) { cv[r] = sv[lane + 64 * r]; ci[r] = si[lane + 64 * r]; }

    float ev[K]; int ei[K];
#pragma unroll
    for (int k = 0; k < K; ++k) {
      float vmax = -INFINITY; int imax = 0x7fffffff;
#pragma unroll
      for (int r = 0; r < 4; ++r)
        if (cv[r] > vmax || (cv[r] == vmax && ci[r] < imax)) { vmax = cv[r]; imax = ci[r]; }
#pragma unroll
      for (int off = 32; off; off >>= 1) {
        const float ov = __shfl_down(vmax, off);
        const int   oi = __shfl_down(imax, off);
        if (ov > vmax || (ov == vmax && oi < imax)) { vmax = ov; imax = oi; }
      }
      vmax = __shfl(vmax, 0); imax = __shfl(imax, 0);
      ev[k] = vmax; ei[k] = imax;        // static index (loop fully unrolled)
#pragma unroll
      for (int r = 0; r < 4; ++r) if (ci[r] == imax) cv[r] = -INFINITY;
    }

    // A' = sum of wave partials + unselected candidates
    float rem = (lane < 16) ? ssum[lane] : 0.f;
#pragma unroll
    for (int r = 0; r < 4; ++r) rem += __expf((cv[r] - m0) * 1.5f);
#pragma unroll
    for (int off = 32; off; off >>= 1) rem += __shfl_down(rem, off);

    if (lane == 0) {
      float T = 0.f; float c[K];
#pragma unroll
      for (int j = K - 1; j >= 0; --j) { T += __expf((ev[j] - m0) * 1.5f); c[j] = 1.0f / (rem + T); }
      float* wrow = ws + (size_t)b * ROW_WS;
#pragma unroll
      for (int j = 0; j < K; ++j) wrow[j] = c[j];
      int* wi = (int*)(wrow + K);
#pragma unroll
      for (int j = 0; j < K; ++j) wi[j] = ei[j];
      wrow[32] = m0;
    }
  }
}

// ---------------- Phase 2: write st (one-hot) and softs (E * c_k) ----------------
// Each thread handles 4 consecutive n; 16 k-planes; nontemporal float4 stores.
__global__ __launch_bounds__(256)
void gtk_phase2(const float* __restrict__ logits, const float* __restrict__ gumbel,
                const float* __restrict__ ws, float* __restrict__ st,
                float* __restrict__ softs) {
  const int gid = blockIdx.x * 256 + threadIdx.x;
  const int i4  = gid << 2;            // element index into [B*N]
  const int b   = i4 >> 14;            // / N (uniform per block: 16 blocks/row)
  const int n0  = i4 & (N - 1);

  __shared__ float sc[K];
  __shared__ int   si[K];
  __shared__ float sm0;
  if (threadIdx.x < K) {
    sc[threadIdx.x] = ws[(size_t)b * ROW_WS + threadIdx.x];
    si[threadIdx.x] = ((const int*)(ws + (size_t)b * ROW_WS + K))[threadIdx.x];
  }
  if (threadIdx.x == 0) sm0 = ws[(size_t)b * ROW_WS + 32];
  __syncthreads();

  const f4 lv = *(const f4*)(logits + i4);
  const f4 gv = *(const f4*)(gumbel + i4);
  const float m0 = sm0;
  float E[4];
#pragma unroll
  for (int e = 0; e < 4; ++e) E[e] = __expf((lv[e] + gv[e] - m0) * 1.5f);

  // selection step (if any) for each of my 4 elements; K = never selected
  int js[4] = {K, K, K, K};
#pragma unroll
  for (int j = 0; j < K; ++j) {
    const int idx = si[j];
#pragma unroll
    for (int e = 0; e < 4; ++e)
      if (idx == n0 + e) js[e] = j;
  }

  const size_t plane = (size_t)B * N;
#pragma unroll
  for (int k = 0; k < K; ++k) {
    const float ck = sc[k];
    f4 s, h;
#pragma unroll
    for (int e = 0; e < 4; ++e) {
      s[e] = (js[e] < k) ? 0.f : E[e] * ck;
      h[e] = (js[e] == k) ? 1.f : 0.f;
    }
    __builtin_nontemporal_store(s, (f4*)(softs + k * plane + i4));
    __builtin_nontemporal_store(h, (f4*)(st    + k * plane + i4));
  }
}

extern "C" void kernel_launch(void* const* d_in, const int* in_sizes, int n_in,
                              void* d_out, int out_size, void* d_ws, size_t ws_size,
                              hipStream_t stream) {
  const float* logits = (const float*)d_in[0];
  const float* gumbel = (const float*)d_in[1];
  float* st    = (float*)d_out;                      // [K,B,N]
  float* softs = st + (size_t)K * B * N;             // [K,B,N]
  float* ws    = (float*)d_ws;

  gtk_phase1<<<B, 1024, 0, stream>>>(logits, gumbel, ws);
  gtk_phase2<<<(B * N / 4) / 256, 256, 0, stream>>>(logits, gumbel, ws, st, softs);
}